// Round 1
// baseline (5076.155 us; speedup 1.0000x reference)
//
#include <hip/hip_runtime.h>

typedef _Float16 h2 __attribute__((ext_vector_type(2)));
typedef _Float16 h8 __attribute__((ext_vector_type(8)));
typedef float f4 __attribute__((ext_vector_type(4)));

// ---------------- convert fp32 -> f16 ----------------
__global__ void cvt_f32_f16(const float* __restrict__ s, _Float16* __restrict__ d, int n) {
    int i = blockIdx.x * blockDim.x + threadIdx.x;
    if (i < n) d[i] = (_Float16)s[i];
}

// ---------------- x_proj GEMM: C[M][768] = A[M][256] * Bt[768][256]^T + bias ----------------
// A is fp32 (layer 1 input) or f16 (layer 2 input = y1h). Bt rows are N-major, K-contiguous.
template<bool AF16>
__global__ __launch_bounds__(256, 2) void gemm_xproj(
    const void* __restrict__ Ap, const _Float16* __restrict__ Bt,
    const float* __restrict__ bias, float* __restrict__ C)
{
    __shared__ __align__(16) _Float16 As[128 * 40];  // 128 rows x 32 (pad to 40) f16
    __shared__ __align__(16) _Float16 Bs[128 * 40];
    const int tid = threadIdx.x;
    const size_t m0 = (size_t)blockIdx.x * 128;
    const int n0 = blockIdx.y * 128;
    const int lane = tid & 63, wave = tid >> 6;
    const int wm = wave >> 1, wn = wave & 1;        // 2x2 waves, each 64x64
    const int r16 = lane & 15, kg = lane >> 4;
    f4 acc[4][4] = {};
    for (int k0 = 0; k0 < 256; k0 += 32) {
        if (k0) __syncthreads();
        #pragma unroll
        for (int u = 0; u < 2; ++u) {
            int c = tid + u * 256;                  // 512 chunks of 8 f16
            int row = c >> 2, off = (c & 3) * 8;
            h8 av;
            if constexpr (AF16) {
                av = *(const h8*)((const _Float16*)Ap + (m0 + row) * 256 + k0 + off);
            } else {
                const float* ap = (const float*)Ap + (m0 + row) * 256 + k0 + off;
                f4 f0 = *(const f4*)ap, f1 = *(const f4*)(ap + 4);
                av[0]=(_Float16)f0[0]; av[1]=(_Float16)f0[1]; av[2]=(_Float16)f0[2]; av[3]=(_Float16)f0[3];
                av[4]=(_Float16)f1[0]; av[5]=(_Float16)f1[1]; av[6]=(_Float16)f1[2]; av[7]=(_Float16)f1[3];
            }
            *(h8*)&As[row * 40 + off] = av;
            h8 bv = *(const h8*)(Bt + (size_t)(n0 + row) * 256 + k0 + off);
            *(h8*)&Bs[row * 40 + off] = bv;
        }
        __syncthreads();
        h8 af[4], bf[4];
        #pragma unroll
        for (int mi = 0; mi < 4; ++mi) af[mi] = *(const h8*)&As[(wm*64 + mi*16 + r16) * 40 + kg * 8];
        #pragma unroll
        for (int ni = 0; ni < 4; ++ni) bf[ni] = *(const h8*)&Bs[(wn*64 + ni*16 + r16) * 40 + kg * 8];
        #pragma unroll
        for (int mi = 0; mi < 4; ++mi)
            #pragma unroll
            for (int ni = 0; ni < 4; ++ni)
                acc[mi][ni] = __builtin_amdgcn_mfma_f32_16x16x32_f16(af[mi], bf[ni], acc[mi][ni], 0, 0, 0);
    }
    #pragma unroll
    for (int mi = 0; mi < 4; ++mi)
        #pragma unroll
        for (int ni = 0; ni < 4; ++ni) {
            int col = n0 + wn*64 + ni*16 + r16;
            float bv = bias[col];
            #pragma unroll
            for (int r = 0; r < 4; ++r) {
                int row = wm*64 + mi*16 + kg*4 + r;   // C/D: col=lane&15, row=(lane>>4)*4+reg
                C[(m0 + row) * 768 + col] = acc[mi][ni][r] + bv;
            }
        }
}

// ---------------- recurrent scan: one workgroup per batch, W_hh register-resident f16 ----------------
template<bool OUTF32>
__global__ __launch_bounds__(512, 2) void gru_scan(
    const float* __restrict__ xp,        // [B][T][768] fp32 (x_proj incl. b_ih)
    const _Float16* __restrict__ Whh,    // [768][256] f16
    const float* __restrict__ bhh,       // [768]
    float* __restrict__ o32,             // [B][T][256] (layer 2 -> d_out)
    _Float16* __restrict__ o16)          // [B][T][256] f16 (layer 1 -> next GEMM input)
{
    __shared__ __align__(16) float    hf[2][256];   // fp32 recurrent state (exact)
    __shared__ __align__(16) _Float16 hh[2][256];   // f16 copy for dot2 matvec
    const int b = blockIdx.x;
    const int tid = threadIdx.x;
    const int j = tid >> 1, hlf = tid & 1;          // 2 threads per output j, k halves

    // load this thread's weight slice: rows {j, j+256, j+512}, k in [hlf*128, hlf*128+128)
    h2 wr[64], wz[64], wn[64];
    {
        const h8* p0 = (const h8*)(Whh + (size_t)j * 256 + hlf * 128);
        const h8* p1 = (const h8*)(Whh + (size_t)(j + 256) * 256 + hlf * 128);
        const h8* p2 = (const h8*)(Whh + (size_t)(j + 512) * 256 + hlf * 128);
        #pragma unroll
        for (int k8 = 0; k8 < 16; ++k8) {
            h8 v0 = p0[k8]; __builtin_memcpy(&wr[k8 * 4], &v0, 16);
            h8 v1 = p1[k8]; __builtin_memcpy(&wz[k8 * 4], &v1, 16);
            h8 v2 = p2[k8]; __builtin_memcpy(&wn[k8 * 4], &v2, 16);
        }
    }
    const float br = bhh[j], bz = bhh[j + 256], bn = bhh[j + 512];
    if (tid < 256) { hf[0][tid] = 1.0f; hh[0][tid] = (_Float16)1.0f; }
    __syncthreads();

    const float* xb = xp + (size_t)b * 2048 * 768;
    float xr = xb[j], xz = xb[j + 256], xn = xb[j + 512];
    int cur = 0;
    for (int t = 0; t < 2048; ++t) {
        // prefetch next step's x_proj (latency hidden under matvec)
        const float* xnx = xb + (size_t)(t + 1 < 2048 ? t + 1 : t) * 768;
        float pr = xnx[j], pz = xnx[j + 256], pn = xnx[j + 512];

        float ar = 0.f, az = 0.f, an = 0.f;
        const h8* hv8 = (const h8*)&hh[cur][hlf * 128];
        #pragma unroll
        for (int k8 = 0; k8 < 16; ++k8) {
            h8 hc = hv8[k8];             // broadcast LDS read (2 distinct addrs per wave)
            h2 hp[4]; __builtin_memcpy(&hp, &hc, 16);
            #pragma unroll
            for (int q = 0; q < 4; ++q) {
                int k = k8 * 4 + q;
                ar = __builtin_amdgcn_fdot2(wr[k], hp[q], ar, false);
                az = __builtin_amdgcn_fdot2(wz[k], hp[q], az, false);
                an = __builtin_amdgcn_fdot2(wn[k], hp[q], an, false);
            }
        }
        ar += __shfl_xor(ar, 1);
        az += __shfl_xor(az, 1);
        an += __shfl_xor(an, 1);

        float rg = 1.f / (1.f + __expf(-(xr + ar + br)));
        float zg = 1.f / (1.f + __expf(-(xz + az + bz)));
        float narg = xn + rg * (an + bn);
        float aa = fabsf(narg);
        float e = __expf(-2.f * aa);
        float ng = copysignf((1.f - e) / (1.f + e), narg);   // tanh, overflow-safe
        float hold = hf[cur][j];
        float hnew = (1.f - zg) * ng + zg * hold;

        const int nxt = cur ^ 1;
        if (hlf == 0) {
            hf[nxt][j] = hnew;
            hh[nxt][j] = (_Float16)hnew;
            size_t oi = ((size_t)b * 2048 + t) * 256 + j;
            if constexpr (OUTF32) o32[oi] = hnew; else o16[oi] = (_Float16)hnew;
        }
        __syncthreads();
        cur = nxt;
        xr = pr; xz = pz; xn = pn;
    }
}

// ---------------- launch ----------------
extern "C" void kernel_launch(void* const* d_in, const int* in_sizes, int n_in,
                              void* d_out, int out_size, void* d_ws, size_t ws_size,
                              hipStream_t stream) {
    const float* x    = (const float*)d_in[0];   // [32][2048][256]
    const float* W_ih = (const float*)d_in[1];   // [2][768][256]
    const float* W_hh = (const float*)d_in[2];   // [2][768][256]
    const float* b_ih = (const float*)d_in[3];   // [2][768]
    const float* b_hh = (const float*)d_in[4];   // [2][768]
    float* out = (float*)d_out;                  // [32][2048][256]

    char* ws = (char*)d_ws;
    float*     xproj = (float*)ws;                                   // 201,326,592 B
    _Float16*  Wih_h = (_Float16*)(ws + 201326592);                  //     786,432 B
    _Float16*  Whh_h = (_Float16*)(ws + 201326592 + 786432);         //     786,432 B
    _Float16*  y1h   = (_Float16*)(ws + 201326592 + 2 * 786432);     //  33,554,432 B

    // weights -> f16 (both layers at once)
    cvt_f32_f16<<<1536, 256, 0, stream>>>(W_ih, Wih_h, 393216);
    cvt_f32_f16<<<1536, 256, 0, stream>>>(W_hh, Whh_h, 393216);

    // layer 1
    gemm_xproj<false><<<dim3(512, 6), 256, 0, stream>>>(x, Wih_h, b_ih, xproj);
    gru_scan<false><<<32, 512, 0, stream>>>(xproj, Whh_h, b_hh, nullptr, y1h);

    // layer 2
    gemm_xproj<true><<<dim3(512, 6), 256, 0, stream>>>(y1h, Wih_h + 196608, b_ih + 768, xproj);
    gru_scan<true><<<32, 512, 0, stream>>>(xproj, Whh_h + 196608, b_hh + 768, out, nullptr);
}